// Round 1
// baseline (1039.167 us; speedup 1.0000x reference)
//
#include <hip/hip_runtime.h>
#include <math.h>

// ---------------- CSR build ----------------

__global__ void hist_kernel(const int* __restrict__ ei, int* __restrict__ cnt, int E) {
  int e = blockIdx.x * blockDim.x + threadIdx.x;
  if (e < E) atomicAdd(&cnt[ei[E + e]], 1);
}

__global__ __launch_bounds__(1024) void scan_kernel(int* __restrict__ cnt,
                                                    int* __restrict__ offs, int N) {
  __shared__ int part[1024];
  int tid = threadIdx.x;
  int chunk = (N + 1023) >> 10;
  int s = tid * chunk;
  int epos = s + chunk; if (epos > N) epos = N;
  int sum = 0;
  for (int i = s; i < epos; ++i) sum += cnt[i];
  part[tid] = sum;
  __syncthreads();
  for (int off = 1; off < 1024; off <<= 1) {
    int v = (tid >= off) ? part[tid - off] : 0;
    __syncthreads();
    part[tid] += v;
    __syncthreads();
  }
  int base = part[tid] - sum;  // exclusive prefix of this thread's chunk
  for (int i = s; i < epos; ++i) {
    int c = cnt[i];
    offs[i] = base;
    cnt[i] = base;            // cnt becomes the scatter cursor
    base += c;
  }
  if (tid == 1023) offs[N] = part[1023];
}

__global__ void scatter_kernel(const int* __restrict__ ei, const float* __restrict__ ea,
                               int* __restrict__ cursor, int2* __restrict__ sedge, int E) {
  int e = blockIdx.x * blockDim.x + threadIdx.x;
  if (e >= E) return;
  int d = ei[E + e];
  int posn = atomicAdd(&cursor[d], 1);
  sedge[posn] = make_int2(ei[e], __float_as_int(ea[e]));
}

// ---------------- degree bucket-sort of nodes (balance) ----------------

__global__ void dhist_kernel(const int* __restrict__ offs, int* __restrict__ dh, int N) {
  int n = blockIdx.x * blockDim.x + threadIdx.x;
  if (n >= N) return;
  int deg = offs[n + 1] - offs[n];
  int b = 255 - (deg < 255 ? deg : 255);  // descending degree order
  atomicAdd(&dh[b], 1);
}

__global__ __launch_bounds__(256) void dscan_kernel(const int* __restrict__ dh,
                                                    int* __restrict__ dcur) {
  __shared__ int part[256];
  int tid = threadIdx.x;
  int v = dh[tid];
  part[tid] = v;
  __syncthreads();
  for (int off = 1; off < 256; off <<= 1) {
    int u = (tid >= off) ? part[tid - off] : 0;
    __syncthreads();
    part[tid] += u;
    __syncthreads();
  }
  dcur[tid] = part[tid] - v;
}

__global__ void dscatter_kernel(const int* __restrict__ offs, int* __restrict__ dcur,
                                int* __restrict__ order, int N) {
  int n = blockIdx.x * blockDim.x + threadIdx.x;
  if (n >= N) return;
  int deg = offs[n + 1] - offs[n];
  int b = 255 - (deg < 255 ? deg : 255);
  int posn = atomicAdd(&dcur[b], 1);
  order[posn] = n;
}

// ---------------- P = h @ Wm1[:9] + bm1 (round 0 only; later rounds fused) -------

__global__ __launch_bounds__(64) void premsg_kernel(const float* __restrict__ h,
    const float* __restrict__ Wm1, const float* __restrict__ bm1,
    float* __restrict__ P, int N) {
  int n = blockIdx.x * 64 + threadIdx.x;
  if (n >= N) return;
  float hv[9];
  #pragma unroll
  for (int i = 0; i < 9; ++i) hv[i] = h[(size_t)n * 9 + i];
  float acc[32];
  #pragma unroll
  for (int k = 0; k < 32; ++k) acc[k] = bm1[k];
  #pragma unroll
  for (int i = 0; i < 9; ++i)
    #pragma unroll
    for (int k = 0; k < 32; ++k) acc[k] = fmaf(hv[i], Wm1[i * 32 + k], acc[k]);
  float4* Pv = (float4*)(P + (size_t)n * 32);
  #pragma unroll
  for (int jv = 0; jv < 8; ++jv)
    Pv[jv] = make_float4(acc[jv * 4], acc[jv * 4 + 1], acc[jv * 4 + 2], acc[jv * 4 + 3]);
}

// ---------------- fused aggregate + update (+P-next or +h2o head) ----------------
// 4 lanes per node, edges strided by 4, shfl_xor combine. Degree-sorted order.

template <int MODE>  // 0: write hout + Pout ; 1: final round, write sigmoid head to out
__global__ __launch_bounds__(64) void agg_update_kernel(
    const int* __restrict__ offs, const int2* __restrict__ sedge,
    const int* __restrict__ order,
    const float* __restrict__ Pin, const float* __restrict__ hin,
    float* __restrict__ hout, float* __restrict__ Pout,
    const float* __restrict__ Wm1, const float* __restrict__ bm1,
    const float* __restrict__ Wm2, const float* __restrict__ bm2,
    const float* __restrict__ Wu1, const float* __restrict__ bu1,
    const float* __restrict__ Wu2, const float* __restrict__ bu2,
    const float* __restrict__ Wh1, const float* __restrict__ bh1,
    const float* __restrict__ Wh2, const float* __restrict__ bh2,
    float* __restrict__ out, int N) {
  int gid = blockIdx.x * 64 + threadIdx.x;
  if (gid >= 4 * N) return;
  int n = order[gid >> 2];
  int sub = threadIdx.x & 3;
  int e1 = offs[n + 1];
  float aggr[32];
  #pragma unroll
  for (int k = 0; k < 32; ++k) aggr[k] = 0.f;

  int e = offs[n] + sub;
  float p[32];
  float eav = 0.f;
  if (e < e1) {  // prime the software pipeline
    int2 se = sedge[e];
    eav = __int_as_float(se.y);
    const float4* Pv = (const float4*)(Pin + (size_t)se.x * 32);
    #pragma unroll
    for (int jv = 0; jv < 8; ++jv) {
      float4 v = Pv[jv];
      p[jv*4+0] = v.x; p[jv*4+1] = v.y; p[jv*4+2] = v.z; p[jv*4+3] = v.w;
    }
  }
  for (; e < e1; e += 4) {
    // prefetch next edge's gather under this edge's FMAs
    int en = e + 4;
    int ep = en < e1 ? en : e;
    int2 se = sedge[ep];
    float nea = __int_as_float(se.y);
    const float4* Pv = (const float4*)(Pin + (size_t)se.x * 32);
    float np[32];
    #pragma unroll
    for (int jv = 0; jv < 8; ++jv) {
      float4 v = Pv[jv];
      np[jv*4+0] = v.x; np[jv*4+1] = v.y; np[jv*4+2] = v.z; np[jv*4+3] = v.w;
    }
    // layer-1 tail: h1 = relu(P[src] + ea * Wm1[row 9])
    float h1[32];
    #pragma unroll
    for (int j = 0; j < 32; ++j) h1[j] = fmaxf(fmaf(eav, Wm1[288 + j], p[j]), 0.f);
    // layer-2: t = h1 @ Wm2 + bm2  (uniform weights -> scalar loads)
    float t[32];
    #pragma unroll
    for (int k = 0; k < 32; ++k) t[k] = bm2[k];
    #pragma unroll
    for (int j = 0; j < 32; ++j) {
      float hj = h1[j];
      #pragma unroll
      for (int k = 0; k < 32; ++k) t[k] = fmaf(hj, Wm2[j * 32 + k], t[k]);
    }
    #pragma unroll
    for (int k = 0; k < 32; ++k) aggr[k] += fmaxf(t[k], 0.f);
    eav = nea;
    #pragma unroll
    for (int j = 0; j < 32; ++j) p[j] = np[j];
  }
  // combine the 4 sub-lanes of this node
  #pragma unroll
  for (int k = 0; k < 32; ++k) {
    aggr[k] += __shfl_xor(aggr[k], 1);
    aggr[k] += __shfl_xor(aggr[k], 2);
  }
  // update MLP: u1 = relu([h; aggr] @ Wu1 + bu1); emb = relu(u1 @ Wu2 + bu2)
  float hv[9];
  #pragma unroll
  for (int i = 0; i < 9; ++i) hv[i] = hin[(size_t)n * 9 + i];
  float u1[16];
  #pragma unroll
  for (int q = 0; q < 16; ++q) {
    float a = bu1[q];
    #pragma unroll
    for (int i = 0; i < 9; ++i) a = fmaf(hv[i], Wu1[i * 16 + q], a);
    #pragma unroll
    for (int k = 0; k < 32; ++k) a = fmaf(aggr[k], Wu1[(9 + k) * 16 + q], a);
    u1[q] = fmaxf(a, 0.f);
  }
  float emb[8];
  #pragma unroll
  for (int r = 0; r < 8; ++r) {
    float a = bu2[r];
    #pragma unroll
    for (int q = 0; q < 16; ++q) a = fmaf(u1[q], Wu2[q * 8 + r], a);
    emb[r] = fmaxf(a, 0.f);
  }
  if constexpr (MODE == 0) {
    // fused premessage for next round: P' = h' @ Wm1[:9] + bm1, h' = [state, emb]
    float acc[32];
    #pragma unroll
    for (int k = 0; k < 32; ++k) acc[k] = fmaf(hv[0], Wm1[k], bm1[k]);
    #pragma unroll
    for (int r = 0; r < 8; ++r)
      #pragma unroll
      for (int k = 0; k < 32; ++k) acc[k] = fmaf(emb[r], Wm1[(1 + r) * 32 + k], acc[k]);
    if (sub == 0) {
      hout[(size_t)n * 9] = hv[0];
      #pragma unroll
      for (int r = 0; r < 8; ++r) hout[(size_t)n * 9 + 1 + r] = emb[r];
      float4* Pv = (float4*)(Pout + (size_t)n * 32);
      #pragma unroll
      for (int jv = 0; jv < 8; ++jv)
        Pv[jv] = make_float4(acc[jv*4], acc[jv*4+1], acc[jv*4+2], acc[jv*4+3]);
    }
  } else {
    // h2o head: out = sigmoid(relu(emb @ Wh1 + bh1) @ Wh2 + bh2)
    float o[16];
    #pragma unroll
    for (int q = 0; q < 16; ++q) {
      float a = bh1[q];
      #pragma unroll
      for (int r = 0; r < 8; ++r) a = fmaf(emb[r], Wh1[r * 16 + q], a);
      o[q] = fmaxf(a, 0.f);
    }
    float z = bh2[0];
    #pragma unroll
    for (int q = 0; q < 16; ++q) z = fmaf(o[q], Wh2[q], z);
    if (sub == 0) out[n] = 1.f / (1.f + expf(-z));
  }
}

// ---------------- launch ----------------

extern "C" void kernel_launch(void* const* d_in, const int* in_sizes, int n_in,
                              void* d_out, int out_size, void* d_ws, size_t ws_size,
                              hipStream_t stream) {
  const float* x   = (const float*)d_in[0];
  const int*   ei  = (const int*)d_in[1];
  const float* ea  = (const float*)d_in[2];
  const float* Wm1 = (const float*)d_in[3];
  const float* bm1 = (const float*)d_in[4];
  const float* Wm2 = (const float*)d_in[5];
  const float* bm2 = (const float*)d_in[6];
  const float* Wu1 = (const float*)d_in[7];
  const float* bu1 = (const float*)d_in[8];
  const float* Wu2 = (const float*)d_in[9];
  const float* bu2 = (const float*)d_in[10];
  const float* Wh1 = (const float*)d_in[11];
  const float* bh1 = (const float*)d_in[12];
  const float* Wh2 = (const float*)d_in[13];
  const float* bh2 = (const float*)d_in[14];
  float* out = (float*)d_out;
  const int N = in_sizes[0] / 9;
  const int E = in_sizes[2];

  char* wsb = (char*)d_ws;
  size_t pos = 0;
  auto alloc = [&](size_t b) {
    pos = (pos + 255) & ~(size_t)255;
    char* p = wsb + pos;
    pos += b;
    return (void*)p;
  };
  int*   cnt   = (int*)alloc((size_t)N * 4);        // histogram -> cursor
  int*   offs  = (int*)alloc((size_t)(N + 1) * 4);  // CSR offsets
  int2*  sedge = (int2*)alloc((size_t)E * 8);       // (src, edge_attr bits), dst-sorted
  int*   dh    = (int*)alloc(256 * 4);
  int*   dcur  = (int*)alloc(256 * 4);
  int*   order = (int*)alloc((size_t)N * 4);        // degree-sorted node order
  float* P0    = (float*)alloc((size_t)N * 32 * 4);
  float* P1    = (float*)alloc((size_t)N * 32 * 4);
  float* hA    = (float*)alloc((size_t)N * 9 * 4);
  float* hB    = (float*)alloc((size_t)N * 9 * 4);

  hipMemsetAsync(cnt, 0, (size_t)N * 4, stream);
  hipMemsetAsync(dh, 0, 256 * 4, stream);

  hist_kernel<<<(E + 255) / 256, 256, 0, stream>>>(ei, cnt, E);
  scan_kernel<<<1, 1024, 0, stream>>>(cnt, offs, N);
  scatter_kernel<<<(E + 255) / 256, 256, 0, stream>>>(ei, ea, cnt, sedge, E);
  dhist_kernel<<<(N + 255) / 256, 256, 0, stream>>>(offs, dh, N);
  dscan_kernel<<<1, 256, 0, stream>>>(dh, dcur);
  dscatter_kernel<<<(N + 255) / 256, 256, 0, stream>>>(offs, dcur, order, N);
  premsg_kernel<<<(N + 63) / 64, 64, 0, stream>>>(x, Wm1, bm1, P0, N);

  int gb = (4 * N + 63) / 64;
  agg_update_kernel<0><<<gb, 64, 0, stream>>>(offs, sedge, order, P0, x, hA, P1,
      Wm1, bm1, Wm2, bm2, Wu1, bu1, Wu2, bu2, Wh1, bh1, Wh2, bh2, nullptr, N);
  agg_update_kernel<0><<<gb, 64, 0, stream>>>(offs, sedge, order, P1, hA, hB, P0,
      Wm1, bm1, Wm2, bm2, Wu1, bu1, Wu2, bu2, Wh1, bh1, Wh2, bh2, nullptr, N);
  agg_update_kernel<1><<<gb, 64, 0, stream>>>(offs, sedge, order, P0, hB, nullptr, nullptr,
      Wm1, bm1, Wm2, bm2, Wu1, bu1, Wu2, bu2, Wh1, bh1, Wh2, bh2, out, N);
}

// Round 2
// 1011.479 us; speedup vs baseline: 1.0274x; 1.0274x over previous
//
#include <hip/hip_runtime.h>
#include <math.h>

// ---------------- CSR build ----------------

__global__ void hist_kernel(const int* __restrict__ ei, int* __restrict__ cnt, int E) {
  int e = blockIdx.x * blockDim.x + threadIdx.x;
  if (e < E) atomicAdd(&cnt[ei[E + e]], 1);
}

__global__ __launch_bounds__(1024) void scan_kernel(int* __restrict__ cnt,
                                                    int* __restrict__ offs, int N) {
  __shared__ int part[1024];
  int tid = threadIdx.x;
  int chunk = (N + 1023) >> 10;
  int s = tid * chunk;
  int epos = s + chunk; if (epos > N) epos = N;
  int sum = 0;
  for (int i = s; i < epos; ++i) sum += cnt[i];
  part[tid] = sum;
  __syncthreads();
  for (int off = 1; off < 1024; off <<= 1) {
    int v = (tid >= off) ? part[tid - off] : 0;
    __syncthreads();
    part[tid] += v;
    __syncthreads();
  }
  int base = part[tid] - sum;  // exclusive prefix of this thread's chunk
  for (int i = s; i < epos; ++i) {
    int c = cnt[i];
    offs[i] = base;
    cnt[i] = base;            // cnt becomes the scatter cursor
    base += c;
  }
  if (tid == 1023) offs[N] = part[1023];
}

__global__ void scatter_kernel(const int* __restrict__ ei, const float* __restrict__ ea,
                               int* __restrict__ cursor, int2* __restrict__ sedge, int E) {
  int e = blockIdx.x * blockDim.x + threadIdx.x;
  if (e >= E) return;
  int d = ei[E + e];
  int posn = atomicAdd(&cursor[d], 1);
  sedge[posn] = make_int2(ei[e], __float_as_int(ea[e]));
}

// ---------------- degree bucket-sort of nodes (balance) ----------------

__global__ void dhist_kernel(const int* __restrict__ offs, int* __restrict__ dh, int N) {
  int n = blockIdx.x * blockDim.x + threadIdx.x;
  if (n >= N) return;
  int deg = offs[n + 1] - offs[n];
  int b = 255 - (deg < 255 ? deg : 255);  // descending degree order
  atomicAdd(&dh[b], 1);
}

__global__ __launch_bounds__(256) void dscan_kernel(const int* __restrict__ dh,
                                                    int* __restrict__ dcur) {
  __shared__ int part[256];
  int tid = threadIdx.x;
  int v = dh[tid];
  part[tid] = v;
  __syncthreads();
  for (int off = 1; off < 256; off <<= 1) {
    int u = (tid >= off) ? part[tid - off] : 0;
    __syncthreads();
    part[tid] += u;
    __syncthreads();
  }
  dcur[tid] = part[tid] - v;
}

__global__ void dscatter_kernel(const int* __restrict__ offs, int* __restrict__ dcur,
                                int* __restrict__ order, int N) {
  int n = blockIdx.x * blockDim.x + threadIdx.x;
  if (n >= N) return;
  int deg = offs[n + 1] - offs[n];
  int b = 255 - (deg < 255 ? deg : 255);
  int posn = atomicAdd(&dcur[b], 1);
  order[posn] = n;
}

// ---------------- P = h @ Wm1[:9] + bm1 (round 0 only; later rounds fused) -------

__global__ __launch_bounds__(64) void premsg_kernel(const float* __restrict__ h,
    const float* __restrict__ Wm1, const float* __restrict__ bm1,
    float* __restrict__ P, int N) {
  int n = blockIdx.x * 64 + threadIdx.x;
  if (n >= N) return;
  float hv[9];
  #pragma unroll
  for (int i = 0; i < 9; ++i) hv[i] = h[(size_t)n * 9 + i];
  float acc[32];
  #pragma unroll
  for (int k = 0; k < 32; ++k) acc[k] = bm1[k];
  #pragma unroll
  for (int i = 0; i < 9; ++i)
    #pragma unroll
    for (int k = 0; k < 32; ++k) acc[k] = fmaf(hv[i], Wm1[i * 32 + k], acc[k]);
  float4* Pv = (float4*)(P + (size_t)n * 32);
  #pragma unroll
  for (int jv = 0; jv < 8; ++jv)
    Pv[jv] = make_float4(acc[jv * 4], acc[jv * 4 + 1], acc[jv * 4 + 2], acc[jv * 4 + 3]);
}

// ---------------- fused aggregate + update (+P-next or +h2o head) ----------------
// 4 lanes per node, edges strided by 4, shfl_xor combine. Degree-sorted order.
// __launch_bounds__(64, 1): grid gives only ~12 waves/CU, so let the allocator
// use the full VGPR file — spills (round-0's 71 GB scratch traffic) are fatal.

template <int MODE>  // 0: write hout + Pout ; 1: final round, write sigmoid head to out
__global__ __launch_bounds__(64, 1) void agg_update_kernel(
    const int* __restrict__ offs, const int2* __restrict__ sedge,
    const int* __restrict__ order,
    const float* __restrict__ Pin, const float* __restrict__ hin,
    float* __restrict__ hout, float* __restrict__ Pout,
    const float* __restrict__ Wm1, const float* __restrict__ bm1,
    const float* __restrict__ Wm2, const float* __restrict__ bm2,
    const float* __restrict__ Wu1, const float* __restrict__ bu1,
    const float* __restrict__ Wu2, const float* __restrict__ bu2,
    const float* __restrict__ Wh1, const float* __restrict__ bh1,
    const float* __restrict__ Wh2, const float* __restrict__ bh2,
    float* __restrict__ out, int N) {
  int gid = blockIdx.x * 64 + threadIdx.x;
  if (gid >= 4 * N) return;
  int n = order[gid >> 2];
  int sub = threadIdx.x & 3;
  int e1 = offs[n + 1];
  const float* __restrict__ Wm1t = Wm1 + 288;  // row 9 (edge_attr row)
  float aggr[32];
  #pragma unroll
  for (int k = 0; k < 32; ++k) aggr[k] = 0.f;

  int e = offs[n] + sub;
  float p[32];
  float eav = 0.f;
  if (e < e1) {  // prime the software pipeline
    int2 se = sedge[e];
    eav = __int_as_float(se.y);
    const float4* Pv = (const float4*)(Pin + (size_t)se.x * 32);
    #pragma unroll
    for (int jv = 0; jv < 8; ++jv) {
      float4 v = Pv[jv];
      p[jv*4+0] = v.x; p[jv*4+1] = v.y; p[jv*4+2] = v.z; p[jv*4+3] = v.w;
    }
  }
  for (; e < e1; e += 4) {
    // prefetch next edge's gather; its latency hides under the 1024 FMAs below
    int en = e + 4;
    int ep = en < e1 ? en : e;
    int2 se = sedge[ep];
    float nea = __int_as_float(se.y);
    const float4* Pv = (const float4*)(Pin + (size_t)se.x * 32);
    float np[32];
    #pragma unroll
    for (int jv = 0; jv < 8; ++jv) {
      float4 v = Pv[jv];
      np[jv*4+0] = v.x; np[jv*4+1] = v.y; np[jv*4+2] = v.z; np[jv*4+3] = v.w;
    }
    // layer-1 tail in place: p becomes h1 = relu(P[src] + ea * Wm1[row 9])
    #pragma unroll
    for (int j = 0; j < 32; ++j) p[j] = fmaxf(fmaf(eav, Wm1t[j], p[j]), 0.f);
    // layer-2 in 4 chunks of 8 output channels (keeps live set in registers)
    #pragma unroll
    for (int c = 0; c < 4; ++c) {
      float t[8];
      #pragma unroll
      for (int k = 0; k < 8; ++k) t[k] = bm2[c * 8 + k];
      #pragma unroll
      for (int j = 0; j < 32; ++j) {
        float hj = p[j];
        #pragma unroll
        for (int k = 0; k < 8; ++k) t[k] = fmaf(hj, Wm2[j * 32 + c * 8 + k], t[k]);
      }
      #pragma unroll
      for (int k = 0; k < 8; ++k) aggr[c * 8 + k] += fmaxf(t[k], 0.f);
    }
    eav = nea;
    #pragma unroll
    for (int j = 0; j < 32; ++j) p[j] = np[j];
  }
  // combine the 4 sub-lanes of this node
  #pragma unroll
  for (int k = 0; k < 32; ++k) {
    aggr[k] += __shfl_xor(aggr[k], 1);
    aggr[k] += __shfl_xor(aggr[k], 2);
  }
  // update MLP: u1 = relu([h; aggr] @ Wu1 + bu1); emb = relu(u1 @ Wu2 + bu2)
  float hv[9];
  #pragma unroll
  for (int i = 0; i < 9; ++i) hv[i] = hin[(size_t)n * 9 + i];
  float u1[16];
  #pragma unroll
  for (int q = 0; q < 16; ++q) {
    float a = bu1[q];
    #pragma unroll
    for (int i = 0; i < 9; ++i) a = fmaf(hv[i], Wu1[i * 16 + q], a);
    #pragma unroll
    for (int k = 0; k < 32; ++k) a = fmaf(aggr[k], Wu1[(9 + k) * 16 + q], a);
    u1[q] = fmaxf(a, 0.f);
  }
  float emb[8];
  #pragma unroll
  for (int r = 0; r < 8; ++r) {
    float a = bu2[r];
    #pragma unroll
    for (int q = 0; q < 16; ++q) a = fmaf(u1[q], Wu2[q * 8 + r], a);
    emb[r] = fmaxf(a, 0.f);
  }
  if constexpr (MODE == 0) {
    // fused premessage for next round: P' = h' @ Wm1[:9] + bm1, h' = [state, emb]
    float acc[32];
    #pragma unroll
    for (int k = 0; k < 32; ++k) acc[k] = fmaf(hv[0], Wm1[k], bm1[k]);
    #pragma unroll
    for (int r = 0; r < 8; ++r)
      #pragma unroll
      for (int k = 0; k < 32; ++k) acc[k] = fmaf(emb[r], Wm1[(1 + r) * 32 + k], acc[k]);
    if (sub == 0) {
      hout[(size_t)n * 9] = hv[0];
      #pragma unroll
      for (int r = 0; r < 8; ++r) hout[(size_t)n * 9 + 1 + r] = emb[r];
      float4* Pv = (float4*)(Pout + (size_t)n * 32);
      #pragma unroll
      for (int jv = 0; jv < 8; ++jv)
        Pv[jv] = make_float4(acc[jv*4], acc[jv*4+1], acc[jv*4+2], acc[jv*4+3]);
    }
  } else {
    // h2o head: out = sigmoid(relu(emb @ Wh1 + bh1) @ Wh2 + bh2)
    float o[16];
    #pragma unroll
    for (int q = 0; q < 16; ++q) {
      float a = bh1[q];
      #pragma unroll
      for (int r = 0; r < 8; ++r) a = fmaf(emb[r], Wh1[r * 16 + q], a);
      o[q] = fmaxf(a, 0.f);
    }
    float z = bh2[0];
    #pragma unroll
    for (int q = 0; q < 16; ++q) z = fmaf(o[q], Wh2[q], z);
    if (sub == 0) out[n] = 1.f / (1.f + expf(-z));
  }
}

// ---------------- launch ----------------

extern "C" void kernel_launch(void* const* d_in, const int* in_sizes, int n_in,
                              void* d_out, int out_size, void* d_ws, size_t ws_size,
                              hipStream_t stream) {
  const float* x   = (const float*)d_in[0];
  const int*   ei  = (const int*)d_in[1];
  const float* ea  = (const float*)d_in[2];
  const float* Wm1 = (const float*)d_in[3];
  const float* bm1 = (const float*)d_in[4];
  const float* Wm2 = (const float*)d_in[5];
  const float* bm2 = (const float*)d_in[6];
  const float* Wu1 = (const float*)d_in[7];
  const float* bu1 = (const float*)d_in[8];
  const float* Wu2 = (const float*)d_in[9];
  const float* bu2 = (const float*)d_in[10];
  const float* Wh1 = (const float*)d_in[11];
  const float* bh1 = (const float*)d_in[12];
  const float* Wh2 = (const float*)d_in[13];
  const float* bh2 = (const float*)d_in[14];
  float* out = (float*)d_out;
  const int N = in_sizes[0] / 9;
  const int E = in_sizes[2];

  char* wsb = (char*)d_ws;
  size_t pos = 0;
  auto alloc = [&](size_t b) {
    pos = (pos + 255) & ~(size_t)255;
    char* p = wsb + pos;
    pos += b;
    return (void*)p;
  };
  int*   cnt   = (int*)alloc((size_t)N * 4);        // histogram -> cursor
  int*   offs  = (int*)alloc((size_t)(N + 1) * 4);  // CSR offsets
  int2*  sedge = (int2*)alloc((size_t)E * 8);       // (src, edge_attr bits), dst-sorted
  int*   dh    = (int*)alloc(256 * 4);
  int*   dcur  = (int*)alloc(256 * 4);
  int*   order = (int*)alloc((size_t)N * 4);        // degree-sorted node order
  float* P0    = (float*)alloc((size_t)N * 32 * 4);
  float* P1    = (float*)alloc((size_t)N * 32 * 4);
  float* hA    = (float*)alloc((size_t)N * 9 * 4);
  float* hB    = (float*)alloc((size_t)N * 9 * 4);

  hipMemsetAsync(cnt, 0, (size_t)N * 4, stream);
  hipMemsetAsync(dh, 0, 256 * 4, stream);

  premsg_kernel<<<(N + 63) / 64, 64, 0, stream>>>(x, Wm1, bm1, P0, N);
  hist_kernel<<<(E + 255) / 256, 256, 0, stream>>>(ei, cnt, E);
  scan_kernel<<<1, 1024, 0, stream>>>(cnt, offs, N);
  scatter_kernel<<<(E + 255) / 256, 256, 0, stream>>>(ei, ea, cnt, sedge, E);
  dhist_kernel<<<(N + 255) / 256, 256, 0, stream>>>(offs, dh, N);
  dscan_kernel<<<1, 256, 0, stream>>>(dh, dcur);
  dscatter_kernel<<<(N + 255) / 256, 256, 0, stream>>>(offs, dcur, order, N);

  int gb = (4 * N + 63) / 64;
  agg_update_kernel<0><<<gb, 64, 0, stream>>>(offs, sedge, order, P0, x, hA, P1,
      Wm1, bm1, Wm2, bm2, Wu1, bu1, Wu2, bu2, Wh1, bh1, Wh2, bh2, nullptr, N);
  agg_update_kernel<0><<<gb, 64, 0, stream>>>(offs, sedge, order, P1, hA, hB, P0,
      Wm1, bm1, Wm2, bm2, Wu1, bu1, Wu2, bu2, Wh1, bh1, Wh2, bh2, nullptr, N);
  agg_update_kernel<1><<<gb, 64, 0, stream>>>(offs, sedge, order, P0, hB, nullptr, nullptr,
      Wm1, bm1, Wm2, bm2, Wu1, bu1, Wu2, bu2, Wh1, bh1, Wh2, bh2, out, N);
}